// Round 9
// baseline (151.185 us; speedup 1.0000x reference)
//
#include <hip/hip_runtime.h>
#include <hip/hip_bf16.h>
#include <stdint.h>

// Problem constants: B=4, CIN=COUT=256, H=W=64, 3x3, pad=1, stride=1, dil=1
#define KDIM 2304   // CIN * 9, GEMM K
#define OUTN 4194304  // 4*256*64*64 output elements

typedef __bf16 bf16_t;
typedef bf16_t bf16x8 __attribute__((ext_vector_type(8)));
typedef float f32x4 __attribute__((ext_vector_type(4)));
typedef float f32x2 __attribute__((ext_vector_type(2)));

__device__ __forceinline__ float b2f_lo(uint32_t u) {
  union { uint32_t i; float f; } c; c.i = u << 16; return c.f;
}
__device__ __forceinline__ float b2f_hi(uint32_t u) {
  union { uint32_t i; float f; } c; c.i = u & 0xffff0000u; return c.f;
}
__device__ __forceinline__ uint32_t pk_bf16(float a, float b) {
  __hip_bfloat162 h = __float22bfloat162_rn(make_float2(a, b));
  union { __hip_bfloat162 h; uint32_t u; } c; c.h = h; return c.u;
}

// async 16B global -> LDS; lds dst wave-uniform, HW adds lane*16
__device__ __forceinline__ void g2lds16(const uint16_t* g, uint16_t* l) {
  __builtin_amdgcn_global_load_lds((const __attribute__((address_space(1))) void*)g,
                                   (__attribute__((address_space(3))) void*)l,
                                   16, 0, 0);
}

// ---------------- merged prep kernel
// blocks [0,2048): x [4][256][64][64] f32 -> xt [4][64][64][256] bf16
// blocks [2048,2304): weight [256][256][3][3] f32 -> wt [cout][tap*256+cin] bf16
__global__ __launch_bounds__(256) void k_prep(const float* __restrict__ x,
                                              uint16_t* __restrict__ xt,
                                              const float* __restrict__ w,
                                              uint16_t* __restrict__ wt) {
  int tid = threadIdx.x;
  if (blockIdx.x < 2048) {
    __shared__ float tile[32][65];
    int b = blockIdx.x >> 9;
    int cgrp = (blockIdx.x >> 6) & 7;
    int sgrp = blockIdx.x & 63;
    int c0 = cgrp << 5, s0 = sgrp << 6;
#pragma unroll
    for (int it = 0; it < 2; ++it) {
      int f = tid + it * 256;
      int rr = f >> 4, col = (f & 15) << 2;
      float4 v = *(const float4*)&x[((size_t)(b * 256 + c0 + rr)) * 4096 + s0 + col];
      tile[rr][col + 0] = v.x;
      tile[rr][col + 1] = v.y;
      tile[rr][col + 2] = v.z;
      tile[rr][col + 3] = v.w;
    }
    __syncthreads();
    int sp = tid >> 2, cg = tid & 3;
    uint4 o;
    o.x = pk_bf16(tile[cg * 8 + 0][sp], tile[cg * 8 + 1][sp]);
    o.y = pk_bf16(tile[cg * 8 + 2][sp], tile[cg * 8 + 3][sp]);
    o.z = pk_bf16(tile[cg * 8 + 4][sp], tile[cg * 8 + 5][sp]);
    o.w = pk_bf16(tile[cg * 8 + 6][sp], tile[cg * 8 + 7][sp]);
    *(uint4*)&xt[((size_t)b * 4096 + s0 + sp) * 256 + c0 + cg * 8] = o;
  } else {
    __shared__ float wl[2304];
    int cout = blockIdx.x - 2048;
    const float* wrow = w + (size_t)cout * 2304;
    for (int i = tid; i < 576; i += 256)
      *(float4*)&wl[i * 4] = *(const float4*)&wrow[i * 4];
    __syncthreads();
    uint16_t* wdst = wt + (size_t)cout * KDIM + tid;
#pragma unroll
    for (int t = 0; t < 9; ++t)
      wdst[t * 256] = (uint16_t)(pk_bf16(wl[tid * 9 + t], 0.f) & 0xffffu);
  }
}

// ---------------- bilinear-deform im2col -> cols [n][tap*256+c] bf16
// 1024 blocks = (b, ho, wo-quarter); 256 threads = 4 waves.
__global__ __launch_bounds__(256) void k_im2col(const uint16_t* __restrict__ xt,
                                                const float* __restrict__ off,
                                                const float* __restrict__ msk,
                                                uint16_t* __restrict__ cols) {
  __shared__ float s_off[18 * 16];
  __shared__ float s_msk[9 * 16];
  int blk = blockIdx.x;
  int wq = blk & 3;
  int ho = (blk >> 2) & 63;
  int b = blk >> 8;
  int w0 = wq << 4;
  int tid = threadIdx.x;
  for (int i = tid; i < 18 * 16; i += 256) {
    int ch = i >> 4, woi = i & 15;
    s_off[i] = off[((size_t)(b * 18 + ch)) * 4096 + ho * 64 + w0 + woi];
  }
  for (int i = tid; i < 9 * 16; i += 256) {
    int ch = i >> 4, woi = i & 15;
    s_msk[i] = msk[((size_t)(b * 9 + ch)) * 4096 + ho * 64 + w0 + woi];
  }
  __syncthreads();
  int wv = tid >> 6, lane = tid & 63;
  int half = lane >> 5, li = lane & 31;
  int c8 = li << 3;
  const uint16_t* base = xt + (size_t)b * 4096 * 256;
  uint16_t* cbase = cols + ((size_t)b * 4096 + (size_t)ho * 64 + w0) * KDIM;
  for (int p = wv; p < 72; p += 4) {
    int s = 2 * p + half;        // 0..143 = k*16 + woi
    int k = s >> 4, woi = s & 15;
    int kh = k / 3, kw = k - kh * 3;
    float dy = s_off[(2 * k) * 16 + woi];
    float dx = s_off[(2 * k + 1) * 16 + woi];
    float mm = s_msk[k * 16 + woi];
    float sy = (float)(ho - 1 + kh) + dy;
    float sx = (float)(w0 + woi - 1 + kw) + dx;
    float fy = floorf(sy), fx = floorf(sx);
    int y0 = (int)fy, x0 = (int)fx;
    float wy = sy - fy, wx = sx - fx;
    f32x2 a0 = {0.f, 0.f}, a1 = {0.f, 0.f}, a2 = {0.f, 0.f}, a3 = {0.f, 0.f};
#pragma unroll
    for (int cy = 0; cy < 2; ++cy) {
#pragma unroll
      for (int cx = 0; cx < 2; ++cx) {
        int y = y0 + cy, x = x0 + cx;
        float w = (cy ? wy : 1.f - wy) * (cx ? wx : 1.f - wx);
        bool v = ((unsigned)y < 64u) && ((unsigned)x < 64u);
        w = v ? w : 0.f;
        int yc = min(max(y, 0), 63), xc = min(max(x, 0), 63);
        const uint4 d = *(const uint4*)(base + (((size_t)yc * 64 + xc) * 256 + c8));
        f32x2 ww = {w, w};
        a0 += ww * f32x2{b2f_lo(d.x), b2f_hi(d.x)};
        a1 += ww * f32x2{b2f_lo(d.y), b2f_hi(d.y)};
        a2 += ww * f32x2{b2f_lo(d.z), b2f_hi(d.z)};
        a3 += ww * f32x2{b2f_lo(d.w), b2f_hi(d.w)};
      }
    }
    f32x2 mm2 = {mm, mm};
    a0 *= mm2; a1 *= mm2; a2 *= mm2; a3 *= mm2;
    uint4 o;
    o.x = pk_bf16(a0.x, a0.y);
    o.y = pk_bf16(a1.x, a1.y);
    o.z = pk_bf16(a2.x, a2.y);
    o.w = pk_bf16(a3.x, a3.y);
    *(uint4*)(cbase + (size_t)woi * KDIM + k * 256 + c8) = o;
  }
}

// ---------------- split-K GEMM (partial buffers, NO atomics)
// C[m][n] = sum_k A[m][k] * B[n][k]; A = wt [256][2304], B = cols [16384][2304]
// 128x128 tile, BK=32; grid dim3(128, 2, NSPLIT). klen = KDIM / NSPLIT.
// kz=0 -> out (with bias); kz>0 -> partial buffer kz-1.
#define BM 128
#define BN 128
#define BK 32
__global__ __launch_bounds__(256) void k_gemm(const uint16_t* __restrict__ A,
                                              const uint16_t* __restrict__ Bm,
                                              const float* __restrict__ bias,
                                              float* __restrict__ out,
                                              float* __restrict__ part,
                                              int klen) {
  __shared__ __align__(16) uint16_t As[BM * BK];
  __shared__ __align__(16) uint16_t Bs[BN * BK];
  int tid = threadIdx.x;
  int lane = tid & 63, wv = tid >> 6;
  int wm = wv >> 1, wn = wv & 1;            // 2x2 wave grid, 64x64 each
  int m0 = blockIdx.y * BM, n0 = blockIdx.x * BN;
  int kz = blockIdx.z;
  int kbeg = kz * klen, kend = kbeg + klen;
  int q = lane >> 4, r = lane & 15;

  f32x4 acc[4][4];
#pragma unroll
  for (int i = 0; i < 4; ++i)
#pragma unroll
    for (int j = 0; j < 4; ++j) acc[i][j] = f32x4{0.f, 0.f, 0.f, 0.f};

  const uint16_t* a0p = A + (size_t)(m0 + (tid >> 2)) * KDIM + (tid & 3) * 8;
  const uint16_t* a1p = A + (size_t)(m0 + 64 + (tid >> 2)) * KDIM + (tid & 3) * 8;
  const uint16_t* b0p = Bm + (size_t)(n0 + (tid >> 2)) * KDIM + (tid & 3) * 8;
  const uint16_t* b1p = Bm + (size_t)(n0 + 64 + (tid >> 2)) * KDIM + (tid & 3) * 8;
  uint16_t* as0 = &As[tid * 8];
  uint16_t* as1 = &As[2048 + tid * 8];
  uint16_t* bs0 = &Bs[tid * 8];
  uint16_t* bs1 = &Bs[2048 + tid * 8];

  for (int k0 = kbeg; k0 < kend; k0 += BK) {
    g2lds16(a0p + k0, as0);
    g2lds16(a1p + k0, as1);
    g2lds16(b0p + k0, bs0);
    g2lds16(b1p + k0, bs1);
    __syncthreads();
    bf16x8 af[4], bfr[4];
#pragma unroll
    for (int mi = 0; mi < 4; ++mi)
      af[mi] = *(const bf16x8*)&As[(wm * 64 + mi * 16 + r) * BK + q * 8];
#pragma unroll
    for (int ni = 0; ni < 4; ++ni)
      bfr[ni] = *(const bf16x8*)&Bs[(wn * 64 + ni * 16 + r) * BK + q * 8];
#pragma unroll
    for (int mi = 0; mi < 4; ++mi)
#pragma unroll
      for (int ni = 0; ni < 4; ++ni)
        acc[mi][ni] = __builtin_amdgcn_mfma_f32_16x16x32_bf16(af[mi], bfr[ni], acc[mi][ni], 0, 0, 0);
    __syncthreads();
  }

  // epilogue: C/D layout col = lane&15 (n), row = q*4 + j (m)
  float* dst = (kz == 0) ? out : (part + (size_t)(kz - 1) * OUTN);
#pragma unroll
  for (int mi = 0; mi < 4; ++mi) {
#pragma unroll
    for (int j = 0; j < 4; ++j) {
      int m = m0 + wm * 64 + mi * 16 + q * 4 + j;
      float bv = (kz == 0) ? bias[m] : 0.f;
#pragma unroll
      for (int ni = 0; ni < 4; ++ni) {
        int n = n0 + wn * 64 + ni * 16 + r;
        int b = n >> 12, p = n & 4095;
        dst[((size_t)(b * 256 + m)) * 4096 + p] = acc[mi][ni][j] + bv;
      }
    }
  }
}

// ---------------- out += p0 + p1 + p2  (float4 per thread; grid*256*4 == OUTN)
__global__ __launch_bounds__(256) void k_reduce(float* __restrict__ out,
                                                const float* __restrict__ part) {
  size_t i = ((size_t)blockIdx.x * 256 + threadIdx.x) * 4;
  float4 o = *(const float4*)&out[i];
  float4 a = *(const float4*)&part[i];
  float4 b = *(const float4*)&part[(size_t)OUTN + i];
  float4 c = *(const float4*)&part[(size_t)2 * OUTN + i];
  o.x += a.x + b.x + c.x;
  o.y += a.y + b.y + c.y;
  o.z += a.z + b.z + c.z;
  o.w += a.w + b.w + c.w;
  *(float4*)&out[i] = o;
}

extern "C" void kernel_launch(void* const* d_in, const int* in_sizes, int n_in,
                              void* d_out, int out_size, void* d_ws, size_t ws_size,
                              hipStream_t stream) {
  (void)in_sizes; (void)n_in; (void)out_size;
  const float* x      = (const float*)d_in[0];  // [4][256][64][64]
  const float* offset = (const float*)d_in[1];  // [4][18][64][64]
  const float* mask   = (const float*)d_in[2];  // [4][9][64][64]
  const float* weight = (const float*)d_in[3];  // [256][256][3][3]
  const float* bias   = (const float*)d_in[4];  // [256]
  float* out = (float*)d_out;                   // [4][256][64][64]

  uint8_t* ws = (uint8_t*)d_ws;
  uint16_t* xt   = (uint16_t*)ws;               // 8,388,608 B : NHWC bf16
  uint16_t* wt   = (uint16_t*)(ws + 8388608);   // 1,179,648 B : [cout][tap*256+cin]
  uint16_t* cols = (uint16_t*)(ws + 9568256);   // 75,497,472 B: [n][tap*256+c]
  float*    part = (float*)(ws + 85065728);     // 50,331,648 B: 3 fp32 partials
  // ws usage with split-K: 135,397,376 B. Fall back if workspace is smaller.
  const bool split = ws_size >= 135397376ULL;

  k_prep<<<dim3(2304), 256, 0, stream>>>(x, xt, weight, wt);
  k_im2col<<<dim3(1024), 256, 0, stream>>>(xt, offset, mask, cols);
  if (split) {
    k_gemm<<<dim3(128, 2, 4), 256, 0, stream>>>(wt, cols, bias, out, part, KDIM / 4);
    k_reduce<<<dim3(4096), 256, 0, stream>>>(out, part);  // 4096*256*4 == OUTN
  } else {
    k_gemm<<<dim3(128, 2, 1), 256, 0, stream>>>(wt, cols, bias, out, part, KDIM);
  }
}

// Round 10
// 138.488 us; speedup vs baseline: 1.0917x; 1.0917x over previous
//
#include <hip/hip_runtime.h>
#include <hip/hip_bf16.h>
#include <stdint.h>

// Problem constants: B=4, CIN=COUT=256, H=W=64, 3x3, pad=1, stride=1, dil=1
#define KDIM 2304     // CIN * 9, GEMM K
#define OUTN 4194304  // 4*256*64*64 output elements
#define NSPLIT 2
#define KLEN (KDIM / NSPLIT)  // 1152
#define NSTEP (KLEN / 32)     // 36

typedef __bf16 bf16_t;
typedef bf16_t bf16x8 __attribute__((ext_vector_type(8)));
typedef float f32x4 __attribute__((ext_vector_type(4)));
typedef float f32x2 __attribute__((ext_vector_type(2)));

__device__ __forceinline__ float b2f_lo(uint32_t u) {
  union { uint32_t i; float f; } c; c.i = u << 16; return c.f;
}
__device__ __forceinline__ float b2f_hi(uint32_t u) {
  union { uint32_t i; float f; } c; c.i = u & 0xffff0000u; return c.f;
}
__device__ __forceinline__ uint32_t pk_bf16(float a, float b) {
  __hip_bfloat162 h = __float22bfloat162_rn(make_float2(a, b));
  union { __hip_bfloat162 h; uint32_t u; } c; c.h = h; return c.u;
}

// ---------------- merged prep kernel
// blocks [0,2048): x [4][256][64][64] f32 -> xt [4][64][64][256] bf16
// blocks [2048,2304): weight [256][256][3][3] f32 -> wt [cout][tap*256+cin] bf16
__global__ __launch_bounds__(256) void k_prep(const float* __restrict__ x,
                                              uint16_t* __restrict__ xt,
                                              const float* __restrict__ w,
                                              uint16_t* __restrict__ wt) {
  int tid = threadIdx.x;
  if (blockIdx.x < 2048) {
    __shared__ float tile[32][65];
    int b = blockIdx.x >> 9;
    int cgrp = (blockIdx.x >> 6) & 7;
    int sgrp = blockIdx.x & 63;
    int c0 = cgrp << 5, s0 = sgrp << 6;
#pragma unroll
    for (int it = 0; it < 2; ++it) {
      int f = tid + it * 256;
      int rr = f >> 4, col = (f & 15) << 2;
      float4 v = *(const float4*)&x[((size_t)(b * 256 + c0 + rr)) * 4096 + s0 + col];
      tile[rr][col + 0] = v.x;
      tile[rr][col + 1] = v.y;
      tile[rr][col + 2] = v.z;
      tile[rr][col + 3] = v.w;
    }
    __syncthreads();
    int sp = tid >> 2, cg = tid & 3;
    uint4 o;
    o.x = pk_bf16(tile[cg * 8 + 0][sp], tile[cg * 8 + 1][sp]);
    o.y = pk_bf16(tile[cg * 8 + 2][sp], tile[cg * 8 + 3][sp]);
    o.z = pk_bf16(tile[cg * 8 + 4][sp], tile[cg * 8 + 5][sp]);
    o.w = pk_bf16(tile[cg * 8 + 6][sp], tile[cg * 8 + 7][sp]);
    *(uint4*)&xt[((size_t)b * 4096 + s0 + sp) * 256 + c0 + cg * 8] = o;
  } else {
    __shared__ float wl[2304];
    int cout = blockIdx.x - 2048;
    const float* wrow = w + (size_t)cout * 2304;
    for (int i = tid; i < 576; i += 256)
      *(float4*)&wl[i * 4] = *(const float4*)&wrow[i * 4];
    __syncthreads();
    uint16_t* wdst = wt + (size_t)cout * KDIM + tid;
#pragma unroll
    for (int t = 0; t < 9; ++t)
      wdst[t * 256] = (uint16_t)(pk_bf16(wl[tid * 9 + t], 0.f) & 0xffffu);
  }
}

// ---------------- bilinear-deform im2col -> cols [n][tap*256+c] bf16
// 1024 blocks = (b, ho, wo-quarter); 256 threads = 4 waves.
__global__ __launch_bounds__(256) void k_im2col(const uint16_t* __restrict__ xt,
                                                const float* __restrict__ off,
                                                const float* __restrict__ msk,
                                                uint16_t* __restrict__ cols) {
  __shared__ float s_off[18 * 16];
  __shared__ float s_msk[9 * 16];
  int blk = blockIdx.x;
  int wq = blk & 3;
  int ho = (blk >> 2) & 63;
  int b = blk >> 8;
  int w0 = wq << 4;
  int tid = threadIdx.x;
  for (int i = tid; i < 18 * 16; i += 256) {
    int ch = i >> 4, woi = i & 15;
    s_off[i] = off[((size_t)(b * 18 + ch)) * 4096 + ho * 64 + w0 + woi];
  }
  for (int i = tid; i < 9 * 16; i += 256) {
    int ch = i >> 4, woi = i & 15;
    s_msk[i] = msk[((size_t)(b * 9 + ch)) * 4096 + ho * 64 + w0 + woi];
  }
  __syncthreads();
  int wv = tid >> 6, lane = tid & 63;
  int half = lane >> 5, li = lane & 31;
  int c8 = li << 3;
  const uint16_t* base = xt + (size_t)b * 4096 * 256;
  uint16_t* cbase = cols + ((size_t)b * 4096 + (size_t)ho * 64 + w0) * KDIM;
  for (int p = wv; p < 72; p += 4) {
    int s = 2 * p + half;        // 0..143 = k*16 + woi
    int k = s >> 4, woi = s & 15;
    int kh = k / 3, kw = k - kh * 3;
    float dy = s_off[(2 * k) * 16 + woi];
    float dx = s_off[(2 * k + 1) * 16 + woi];
    float mm = s_msk[k * 16 + woi];
    float sy = (float)(ho - 1 + kh) + dy;
    float sx = (float)(w0 + woi - 1 + kw) + dx;
    float fy = floorf(sy), fx = floorf(sx);
    int y0 = (int)fy, x0 = (int)fx;
    float wy = sy - fy, wx = sx - fx;
    f32x2 a0 = {0.f, 0.f}, a1 = {0.f, 0.f}, a2 = {0.f, 0.f}, a3 = {0.f, 0.f};
#pragma unroll
    for (int cy = 0; cy < 2; ++cy) {
#pragma unroll
      for (int cx = 0; cx < 2; ++cx) {
        int y = y0 + cy, x = x0 + cx;
        float w = (cy ? wy : 1.f - wy) * (cx ? wx : 1.f - wx);
        bool v = ((unsigned)y < 64u) && ((unsigned)x < 64u);
        w = v ? w : 0.f;
        int yc = min(max(y, 0), 63), xc = min(max(x, 0), 63);
        const uint4 d = *(const uint4*)(base + (((size_t)yc * 64 + xc) * 256 + c8));
        f32x2 ww = {w, w};
        a0 += ww * f32x2{b2f_lo(d.x), b2f_hi(d.x)};
        a1 += ww * f32x2{b2f_lo(d.y), b2f_hi(d.y)};
        a2 += ww * f32x2{b2f_lo(d.z), b2f_hi(d.z)};
        a3 += ww * f32x2{b2f_lo(d.w), b2f_hi(d.w)};
      }
    }
    f32x2 mm2 = {mm, mm};
    a0 *= mm2; a1 *= mm2; a2 *= mm2; a3 *= mm2;
    uint4 o;
    o.x = pk_bf16(a0.x, a0.y);
    o.y = pk_bf16(a1.x, a1.y);
    o.z = pk_bf16(a2.x, a2.y);
    o.w = pk_bf16(a3.x, a3.y);
    *(uint4*)(cbase + (size_t)woi * KDIM + k * 256 + c8) = o;
  }
}

// ---------------- split-K GEMM with REGISTER-PREFETCH double buffer
// C[m][n] = sum_k A[m][k] * B[n][k]; A = wt [256][2304], B = cols [16384][2304]
// 128x128 tile, BK=32; grid dim3(128, 2, 2) = 512 blocks = 2/CU.
// Pipeline per step: issue global loads for step i+1 (to VGPRs) -> barrier ->
// ds_read + MFMA on buf[i&1] -> ds_write regs to buf[(i+1)&1].
// The barrier never waits on global latency (only lgkmcnt).
#define BM 128
#define BN 128
#define BK 32
__global__ __launch_bounds__(256) void k_gemm(const uint16_t* __restrict__ A,
                                              const uint16_t* __restrict__ Bm,
                                              const float* __restrict__ bias,
                                              float* __restrict__ out,
                                              float* __restrict__ part) {
  __shared__ __align__(16) uint16_t As[2][BM * BK];  // 2 x 8 KB
  __shared__ __align__(16) uint16_t Bs[2][BN * BK];  // 2 x 8 KB
  int tid = threadIdx.x;
  int lane = tid & 63, wv = tid >> 6;
  int wm = wv >> 1, wn = wv & 1;            // 2x2 wave grid, 64x64 each
  int m0 = blockIdx.y * BM, n0 = blockIdx.x * BN;
  int kz = blockIdx.z;
  int kbeg = kz * KLEN;
  int q = lane >> 4, r = lane & 15;

  f32x4 acc[4][4];
#pragma unroll
  for (int i = 0; i < 4; ++i)
#pragma unroll
    for (int j = 0; j < 4; ++j) acc[i][j] = f32x4{0.f, 0.f, 0.f, 0.f};

  const uint16_t* a0p = A + (size_t)(m0 + (tid >> 2)) * KDIM + (tid & 3) * 8 + kbeg;
  const uint16_t* a1p = A + (size_t)(m0 + 64 + (tid >> 2)) * KDIM + (tid & 3) * 8 + kbeg;
  const uint16_t* b0p = Bm + (size_t)(n0 + (tid >> 2)) * KDIM + (tid & 3) * 8 + kbeg;
  const uint16_t* b1p = Bm + (size_t)(n0 + 64 + (tid >> 2)) * KDIM + (tid & 3) * 8 + kbeg;

  // step-0 tiles -> regs -> buf 0
  uint4 ra0 = *(const uint4*)a0p;
  uint4 ra1 = *(const uint4*)a1p;
  uint4 rb0 = *(const uint4*)b0p;
  uint4 rb1 = *(const uint4*)b1p;
  *(uint4*)&As[0][tid * 8] = ra0;
  *(uint4*)&As[0][2048 + tid * 8] = ra1;
  *(uint4*)&Bs[0][tid * 8] = rb0;
  *(uint4*)&Bs[0][2048 + tid * 8] = rb1;

  for (int i = 0; i < NSTEP; ++i) {
    int cur = i & 1;
    if (i + 1 < NSTEP) {
      int k1 = (i + 1) * BK;
      ra0 = *(const uint4*)(a0p + k1);
      ra1 = *(const uint4*)(a1p + k1);
      rb0 = *(const uint4*)(b0p + k1);
      rb1 = *(const uint4*)(b1p + k1);
    }
    __syncthreads();   // publish buf[cur] (LDS ops only)
    bf16x8 af[4], bfr[4];
#pragma unroll
    for (int mi = 0; mi < 4; ++mi)
      af[mi] = *(const bf16x8*)&As[cur][(wm * 64 + mi * 16 + r) * BK + q * 8];
#pragma unroll
    for (int ni = 0; ni < 4; ++ni)
      bfr[ni] = *(const bf16x8*)&Bs[cur][(wn * 64 + ni * 16 + r) * BK + q * 8];
#pragma unroll
    for (int mi = 0; mi < 4; ++mi)
#pragma unroll
      for (int ni = 0; ni < 4; ++ni)
        acc[mi][ni] = __builtin_amdgcn_mfma_f32_16x16x32_bf16(af[mi], bfr[ni], acc[mi][ni], 0, 0, 0);
    if (i + 1 < NSTEP) {
      int nb = (i + 1) & 1;
      *(uint4*)&As[nb][tid * 8] = ra0;       // vmcnt wait lands here, after MFMA
      *(uint4*)&As[nb][2048 + tid * 8] = ra1;
      *(uint4*)&Bs[nb][tid * 8] = rb0;
      *(uint4*)&Bs[nb][2048 + tid * 8] = rb1;
    }
  }

  // epilogue: C/D layout col = lane&15 (n), row = q*4 + j (m)
  float* dst = (kz == 0) ? out : part;
#pragma unroll
  for (int mi = 0; mi < 4; ++mi) {
#pragma unroll
    for (int j = 0; j < 4; ++j) {
      int m = m0 + wm * 64 + mi * 16 + q * 4 + j;
      float bv = (kz == 0) ? bias[m] : 0.f;
#pragma unroll
      for (int ni = 0; ni < 4; ++ni) {
        int n = n0 + wn * 64 + ni * 16 + r;
        int b = n >> 12, p = n & 4095;
        dst[((size_t)(b * 256 + m)) * 4096 + p] = acc[mi][ni][j] + bv;
      }
    }
  }
}

// ---------------- out += part  (float4 per thread; 4096*256*4 == OUTN)
__global__ __launch_bounds__(256) void k_reduce(float* __restrict__ out,
                                                const float* __restrict__ part) {
  size_t i = ((size_t)blockIdx.x * 256 + threadIdx.x) * 4;
  float4 o = *(const float4*)&out[i];
  float4 a = *(const float4*)&part[i];
  o.x += a.x;
  o.y += a.y;
  o.z += a.z;
  o.w += a.w;
  *(float4*)&out[i] = o;
}

extern "C" void kernel_launch(void* const* d_in, const int* in_sizes, int n_in,
                              void* d_out, int out_size, void* d_ws, size_t ws_size,
                              hipStream_t stream) {
  (void)in_sizes; (void)n_in; (void)out_size; (void)ws_size;
  const float* x      = (const float*)d_in[0];  // [4][256][64][64]
  const float* offset = (const float*)d_in[1];  // [4][18][64][64]
  const float* mask   = (const float*)d_in[2];  // [4][9][64][64]
  const float* weight = (const float*)d_in[3];  // [256][256][3][3]
  const float* bias   = (const float*)d_in[4];  // [256]
  float* out = (float*)d_out;                   // [4][256][64][64]

  uint8_t* ws = (uint8_t*)d_ws;
  uint16_t* xt   = (uint16_t*)ws;               // 8,388,608 B : NHWC bf16
  uint16_t* wt   = (uint16_t*)(ws + 8388608);   // 1,179,648 B : [cout][tap*256+cin]
  uint16_t* cols = (uint16_t*)(ws + 9568256);   // 75,497,472 B: [n][tap*256+c]
  float*    part = (float*)(ws + 85065728);     // 16,777,216 B: fp32 partial
  // ws usage: 101,842,944 B (R9 proved ws_size >= 135 MB).

  k_prep<<<dim3(2304), 256, 0, stream>>>(x, xt, weight, wt);
  k_im2col<<<dim3(1024), 256, 0, stream>>>(xt, offset, mask, cols);
  k_gemm<<<dim3(128, 2, 2), 256, 0, stream>>>(wt, cols, bias, out, part);
  k_reduce<<<dim3(4096), 256, 0, stream>>>(out, part);
}